// Round 1
// baseline (280.089 us; speedup 1.0000x reference)
//
#include <hip/hip_runtime.h>
#include <math.h>

#define N_NODES 50000
#define S_NEIB 32
#define D_IN 256
#define D_OUT 128
#define ALPHA 0.2f

__device__ __forceinline__ float elu_f(float v) {
    return v > 0.f ? v : (expf(v) - 1.f);
}

// Kernel 1: xw = x@W; s_self = xw@a[:128]; s_neib = xw@a[128:]; out[:, :128] = elu(xw)
// 64 rows per 256-thread block. lane = row, wave = 32-col slice (W index wave-uniform
// -> scalar loads). x tile in LDS at stride 257 (conflict-free b32 reads).
__global__ __launch_bounds__(256) void gemm_score_kernel(
    const float* __restrict__ x, const float* __restrict__ W,
    const float* __restrict__ a, float* __restrict__ xw,
    float* __restrict__ s_self, float* __restrict__ s_neib,
    float* __restrict__ out)
{
    __shared__ float xs[64 * 257];     // 65792 B; reused as transpose buffer
    __shared__ float ps[2][4][64];     // score partials

    const int tid  = threadIdx.x;
    const int lane = tid & 63;
    const int wave = __builtin_amdgcn_readfirstlane(tid >> 6);
    const int colBase = wave * 32;
    const int r0 = blockIdx.x * 64;

    // stage x tile: 64 rows x 256 cols, float4 global loads, scalar LDS writes
    for (int i = 0; i < 16; ++i) {
        int f4  = i * 256 + tid;
        int row = f4 >> 6;
        int c4  = (f4 & 63) << 2;
        float4 v = make_float4(0.f, 0.f, 0.f, 0.f);
        if (r0 + row < N_NODES)
            v = *(const float4*)(x + (size_t)(r0 + row) * D_IN + c4);
        xs[row * 257 + c4 + 0] = v.x;
        xs[row * 257 + c4 + 1] = v.y;
        xs[row * 257 + c4 + 2] = v.z;
        xs[row * 257 + c4 + 3] = v.w;
    }
    __syncthreads();

    float acc[32];
    #pragma unroll
    for (int c = 0; c < 32; ++c) acc[c] = 0.f;

    #pragma unroll 4
    for (int k = 0; k < 256; ++k) {
        float xv = xs[lane * 257 + k];
        const float* Wk = W + k * D_OUT + colBase;   // wave-uniform -> s_load
        #pragma unroll
        for (int c = 0; c < 32; ++c) acc[c] = fmaf(xv, Wk[c], acc[c]);
    }

    // partial attention scores from live accumulators (a[] wave-uniform -> s_load)
    float p_self = 0.f, p_neib = 0.f;
    #pragma unroll
    for (int c = 0; c < 32; ++c) {
        p_self = fmaf(acc[c], a[colBase + c], p_self);
        p_neib = fmaf(acc[c], a[D_OUT + colBase + c], p_neib);
    }
    ps[0][wave][lane] = p_self;
    ps[1][wave][lane] = p_neib;

    __syncthreads();   // all xs reads done; ps visible

    // transpose acc into LDS (reuse xs), stride 132 to spread banks
    float* xpose = xs;
    #pragma unroll
    for (int c = 0; c < 32; ++c)
        xpose[lane * 132 + colBase + c] = acc[c];

    if (tid < 64 && r0 + tid < N_NODES) {
        s_self[r0 + tid] = ps[0][0][tid] + ps[0][1][tid] + ps[0][2][tid] + ps[0][3][tid];
        s_neib[r0 + tid] = ps[1][0][tid] + ps[1][1][tid] + ps[1][2][tid] + ps[1][3][tid];
    }
    __syncthreads();

    // coalesced stores: 2 rows x 128 cols per iteration
    for (int i = 0; i < 32; ++i) {
        int flat = i * 256 + tid;
        int row  = flat >> 7;
        int col  = flat & 127;
        int g    = r0 + row;
        if (g < N_NODES) {
            float v = xpose[row * 132 + col];
            xw[(size_t)g * D_OUT + col] = v;
            out[(size_t)g * (2 * D_OUT) + col] = elu_f(v);
        }
    }
}

// Kernel 2: per-node softmax attention + weighted aggregate. One wave per node.
__global__ __launch_bounds__(256) void aggregate_kernel(
    const int* __restrict__ neibs, const float* __restrict__ xw,
    const float* __restrict__ s_self, const float* __restrict__ s_neib,
    float* __restrict__ out)
{
    const int lane = threadIdx.x & 63;
    const int wave = threadIdx.x >> 6;
    const int n = blockIdx.x * 4 + wave;
    if (n >= N_NODES) return;

    int   idx = 0;
    float e   = -1e30f;
    if (lane < 32) {
        idx = neibs[n * S_NEIB + lane];
        e = s_self[n] + s_neib[idx];
        e = e > 0.f ? e : ALPHA * e;              // LeakyReLU
    }
    // softmax over lanes 0..31 (xor offsets <=16 stay within the low half)
    float m = e;
    #pragma unroll
    for (int d = 16; d >= 1; d >>= 1) m = fmaxf(m, __shfl_xor(m, d));
    float p = (lane < 32) ? __expf(e - m) : 0.f;
    float ssum = p;
    #pragma unroll
    for (int d = 16; d >= 1; d >>= 1) ssum += __shfl_xor(ssum, d);
    float att = p / ssum;

    // h_prime: each lane owns cols {2*lane, 2*lane+1}; 512 B coalesced row gathers
    float accx = 0.f, accy = 0.f;
    #pragma unroll
    for (int s = 0; s < 32; ++s) {
        int   j = __shfl(idx, s);
        float w = __shfl(att, s);
        const float2 v = *(const float2*)(xw + (size_t)j * D_OUT + 2 * lane);
        accx = fmaf(w, v.x, accx);
        accy = fmaf(w, v.y, accy);
    }
    float2 o;
    o.x = elu_f(accx);
    o.y = elu_f(accy);
    *(float2*)(out + (size_t)n * (2 * D_OUT) + D_OUT + 2 * lane) = o;
}

extern "C" void kernel_launch(void* const* d_in, const int* in_sizes, int n_in,
                              void* d_out, int out_size, void* d_ws, size_t ws_size,
                              hipStream_t stream) {
    const float* x     = (const float*)d_in[0];
    const int*   neibs = (const int*)  d_in[1];
    const float* W     = (const float*)d_in[2];
    const float* a     = (const float*)d_in[3];
    float* out = (float*)d_out;

    float* xw     = (float*)d_ws;                       // N*128 floats = 25.6 MB
    float* s_self = xw + (size_t)N_NODES * D_OUT;       // N floats
    float* s_neib = s_self + N_NODES;                   // N floats

    gemm_score_kernel<<<(N_NODES + 63) / 64, 256, 0, stream>>>(
        x, W, a, xw, s_self, s_neib, out);
    aggregate_kernel<<<(N_NODES + 3) / 4, 256, 0, stream>>>(
        neibs, xw, s_self, s_neib, out);
}

// Round 2
// 162.129 us; speedup vs baseline: 1.7276x; 1.7276x over previous
//
#include <hip/hip_runtime.h>
#include <math.h>

#define N_NODES 50000
#define S_NEIB 32
#define D_IN 256
#define D_OUT 128
#define ALPHA 0.2f

typedef __attribute__((ext_vector_type(8))) short bf16x8;   // 8 bf16 = 4 VGPRs
typedef __attribute__((ext_vector_type(4))) float f32x4;    // MFMA C/D

__device__ __forceinline__ float elu_f(float v) {
    return v > 0.f ? v : (expf(v) - 1.f);
}

// fp32 -> bf16 with round-to-nearest-even
__device__ __forceinline__ unsigned short f2bf(float f) {
    unsigned u = __builtin_bit_cast(unsigned, f);
    u += 0x7fffu + ((u >> 16) & 1u);
    return (unsigned short)(u >> 16);
}

// Kernel 1 (bf16 MFMA): xw_bf16 = bf16(x@W); s_self/s_neib = xw@a halves;
// out[:, :128] = elu(xw). 64 rows/block, 4 waves, wave owns a 32-col slice.
// A-frags from LDS bf16 x-tile; B-frags converted on the fly from L2-resident W.
__global__ __launch_bounds__(256) void gemm_score_kernel(
    const float* __restrict__ x, const float* __restrict__ W,
    const float* __restrict__ a, unsigned short* __restrict__ xwb,
    float* __restrict__ s_self, float* __restrict__ s_neib,
    float* __restrict__ out)
{
    __shared__ unsigned short xs[64 * 264];  // 33 KB; stride 264 bf16 (132 words % 32 = 4 -> ~2-way, free)
    __shared__ float ps[2][4][64];

    const int tid  = threadIdx.x;
    const int lane = tid & 63;
    const int wave = tid >> 6;
    const int q    = lane >> 4;     // quad 0..3
    const int t    = lane & 15;
    const int colW = wave * 32;     // wave's column base
    const int r0   = blockIdx.x * 64;

    // stage x tile 64x256 fp32 -> bf16 LDS (float4 loads, b64 LDS writes)
    for (int i = 0; i < 16; ++i) {
        int f4  = i * 256 + tid;
        int row = f4 >> 6;
        int c4  = (f4 & 63) << 2;
        float4 v = make_float4(0.f, 0.f, 0.f, 0.f);
        if (r0 + row < N_NODES)
            v = *(const float4*)(x + (size_t)(r0 + row) * D_IN + c4);
        ushort4 b;
        b.x = f2bf(v.x); b.y = f2bf(v.y); b.z = f2bf(v.z); b.w = f2bf(v.w);
        *(ushort4*)&xs[row * 264 + c4] = b;
    }
    __syncthreads();

    f32x4 acc[4][2];
    #pragma unroll
    for (int mt = 0; mt < 4; ++mt)
        #pragma unroll
        for (int nt = 0; nt < 2; ++nt)
            acc[mt][nt] = (f32x4){0.f, 0.f, 0.f, 0.f};

    #pragma unroll
    for (int kc = 0; kc < 8; ++kc) {
        const int k0 = kc * 32 + q * 8;
        // A[m = mt*16+t][k = k0..k0+7] — one ds_read_b128 per m-tile
        bf16x8 afrag[4];
        #pragma unroll
        for (int mt = 0; mt < 4; ++mt)
            afrag[mt] = *(const bf16x8*)&xs[(mt * 16 + t) * 264 + k0];
        // B[k = k0+j][n = colW+nt*16+t] from global fp32 W (L2-resident), cvt bf16
        bf16x8 bfrag[2];
        #pragma unroll
        for (int nt = 0; nt < 2; ++nt) {
            const float* wp = W + (size_t)k0 * D_OUT + colW + nt * 16 + t;
            #pragma unroll
            for (int j = 0; j < 8; ++j)
                bfrag[nt][j] = (short)f2bf(wp[(size_t)j * D_OUT]);
        }
        #pragma unroll
        for (int mt = 0; mt < 4; ++mt)
            #pragma unroll
            for (int nt = 0; nt < 2; ++nt)
                acc[mt][nt] = __builtin_amdgcn_mfma_f32_16x16x32_bf16(
                    afrag[mt], bfrag[nt], acc[mt][nt], 0, 0, 0);
    }

    // score partials: lane holds D[row=mt*16+q*4+r][col=colW+nt*16+t];
    // reduce over t (xor 1..8 stays inside the quad)
    const float as0 = a[colW + t],         as1 = a[colW + 16 + t];
    const float an0 = a[D_OUT + colW + t], an1 = a[D_OUT + colW + 16 + t];
    #pragma unroll
    for (int mt = 0; mt < 4; ++mt) {
        #pragma unroll
        for (int r = 0; r < 4; ++r) {
            float vs = acc[mt][0][r] * as0 + acc[mt][1][r] * as1;
            float vn = acc[mt][0][r] * an0 + acc[mt][1][r] * an1;
            #pragma unroll
            for (int d = 8; d >= 1; d >>= 1) {
                vs += __shfl_xor(vs, d);
                vn += __shfl_xor(vn, d);
            }
            if (t == 0) {
                int row = mt * 16 + q * 4 + r;
                ps[0][wave][row] = vs;
                ps[1][wave][row] = vn;
            }
        }
    }
    __syncthreads();
    if (tid < 64 && r0 + tid < N_NODES) {
        s_self[r0 + tid] = ps[0][0][tid] + ps[0][1][tid] + ps[0][2][tid] + ps[0][3][tid];
        s_neib[r0 + tid] = ps[1][0][tid] + ps[1][1][tid] + ps[1][2][tid] + ps[1][3][tid];
    }

    // stores: 16-lane (64 B fp32 / 32 B bf16) segments, 4 rows in flight per inst
    #pragma unroll
    for (int mt = 0; mt < 4; ++mt) {
        #pragma unroll
        for (int r = 0; r < 4; ++r) {
            int g = r0 + mt * 16 + q * 4 + r;
            if (g < N_NODES) {
                #pragma unroll
                for (int nt = 0; nt < 2; ++nt) {
                    int col = colW + nt * 16 + t;
                    float v = acc[mt][nt][r];
                    xwb[(size_t)g * D_OUT + col] = f2bf(v);
                    out[(size_t)g * (2 * D_OUT) + col] = elu_f(v);
                }
            }
        }
    }
}

// Kernel 2: per-node softmax attention + aggregate over bf16 xw table.
// One wave/node; lane l owns cols {2l, 2l+1} -> 4 B/lane, 256 B/row transaction.
__global__ __launch_bounds__(256) void aggregate_kernel(
    const int* __restrict__ neibs, const unsigned short* __restrict__ xwb,
    const float* __restrict__ s_self, const float* __restrict__ s_neib,
    float* __restrict__ out)
{
    const int lane = threadIdx.x & 63;
    const int wave = threadIdx.x >> 6;
    const int n = blockIdx.x * 4 + wave;
    if (n >= N_NODES) return;

    int   idx = 0;
    float e   = -1e30f;
    if (lane < 32) {
        idx = neibs[n * S_NEIB + lane];
        e = s_self[n] + s_neib[idx];
        e = e > 0.f ? e : ALPHA * e;            // LeakyReLU
    }
    float m = e;
    #pragma unroll
    for (int d = 16; d >= 1; d >>= 1) m = fmaxf(m, __shfl_xor(m, d));
    float p = (lane < 32) ? __expf(e - m) : 0.f;
    float ssum = p;
    #pragma unroll
    for (int d = 16; d >= 1; d >>= 1) ssum += __shfl_xor(ssum, d);
    float att = p / ssum;

    float accx = 0.f, accy = 0.f;
    #pragma unroll
    for (int s = 0; s < 32; ++s) {
        int   j = __shfl(idx, s);
        float w = __shfl(att, s);
        unsigned v = *(const unsigned*)(xwb + (size_t)j * D_OUT + 2 * lane);
        float lo = __builtin_bit_cast(float, v << 16);
        float hi = __builtin_bit_cast(float, v & 0xffff0000u);
        accx = fmaf(w, lo, accx);
        accy = fmaf(w, hi, accy);
    }
    float2 o;
    o.x = elu_f(accx);
    o.y = elu_f(accy);
    *(float2*)(out + (size_t)n * (2 * D_OUT) + D_OUT + 2 * lane) = o;
}

extern "C" void kernel_launch(void* const* d_in, const int* in_sizes, int n_in,
                              void* d_out, int out_size, void* d_ws, size_t ws_size,
                              hipStream_t stream) {
    const float* x     = (const float*)d_in[0];
    const int*   neibs = (const int*)  d_in[1];
    const float* W     = (const float*)d_in[2];
    const float* a     = (const float*)d_in[3];
    float* out = (float*)d_out;

    unsigned short* xwb = (unsigned short*)d_ws;             // N*128 bf16 = 12.8 MB
    float* s_self = (float*)(xwb + (size_t)N_NODES * D_OUT); // N floats
    float* s_neib = s_self + N_NODES;                        // N floats

    gemm_score_kernel<<<(N_NODES + 63) / 64, 256, 0, stream>>>(
        x, W, a, xwb, s_self, s_neib, out);
    aggregate_kernel<<<(N_NODES + 3) / 4, 256, 0, stream>>>(
        neibs, xwb, s_self, s_neib, out);
}